// Round 1
// baseline (692.659 us; speedup 1.0000x reference)
//
#include <hip/hip_runtime.h>
#include <hip/hip_bf16.h>
#include <stdint.h>

#define B_ 8
#define S_ 4096
#define D_ 512
#define G_ 64
#define R_ 1024
#define NO_ 4096
#define SO_ 3072   /* S_ - R_ */
#define EPS_MERGE 1e-8f
#define EPS_NORM 1e-12f

// workspace byte offsets
#define WS_G     0ull                 // g: 32768*64 f32   = 8388608 B
#define WS_GN    8388608ull           // gn: 32768 f32     = 131072 B
#define WS_KEYS  8519680ull           // keys: 8*4096 u64  = 262144 B
#define WS_KEPT  8781824ull           // kept: 8*3072 u32  = 98304 B
// total: 8880128 B

// ---------------- k1: g = x @ W^T  (M=32768, N=64, K=512) + row norms ----
// 256 blocks x 256 threads; block = 128 rows x 64 g; thread = 8 rows x 4 g.
__global__ __launch_bounds__(256) void k1_proj(const float* __restrict__ x,
                                               const float* __restrict__ W,
                                               float* __restrict__ g,
                                               float* __restrict__ gn) {
  __shared__ float xs[32][132];   // [k][row] transposed chunk (pad 132: 2-way max)
  __shared__ float wc[32][68];    // [k][g]   transposed chunk
  const int tid = threadIdx.x;
  const int gt  = tid & 15;       // 16 g-threads * 4 g
  const int rt  = tid >> 4;       // 16 row-threads * 8 rows
  const int rb  = blockIdx.x * 128;
  const int g0  = gt * 4;
  const int r0  = rt * 8;
  float acc[8][4];
#pragma unroll
  for (int r = 0; r < 8; ++r)
#pragma unroll
    for (int j = 0; j < 4; ++j) acc[r][j] = 0.f;

  for (int kc = 0; kc < 16; ++kc) {
    const int kbase = kc * 32;
    __syncthreads();
    // stage x chunk: 128 rows x 32 k = 1024 float4
#pragma unroll
    for (int i = 0; i < 4; ++i) {
      int f4i = tid + i * 256;
      int row_l = f4i >> 3;
      int kq = f4i & 7;
      const float4 v = *reinterpret_cast<const float4*>(
          &x[(size_t)(rb + row_l) * D_ + kbase + kq * 4]);
      xs[kq * 4 + 0][row_l] = v.x;
      xs[kq * 4 + 1][row_l] = v.y;
      xs[kq * 4 + 2][row_l] = v.z;
      xs[kq * 4 + 3][row_l] = v.w;
    }
    // stage W chunk: 64 g x 32 k = 512 float4
#pragma unroll
    for (int i = 0; i < 2; ++i) {
      int f4i = tid + i * 256;
      int gg = f4i >> 3;
      int kq = f4i & 7;
      const float4 v = *reinterpret_cast<const float4*>(
          &W[(size_t)gg * D_ + kbase + kq * 4]);
      wc[kq * 4 + 0][gg] = v.x;
      wc[kq * 4 + 1][gg] = v.y;
      wc[kq * 4 + 2][gg] = v.z;
      wc[kq * 4 + 3][gg] = v.w;
    }
    __syncthreads();
#pragma unroll
    for (int k = 0; k < 32; ++k) {
      const float4 wv = *reinterpret_cast<const float4*>(&wc[k][g0]);
      const float4 xa = *reinterpret_cast<const float4*>(&xs[k][r0]);
      const float4 xb = *reinterpret_cast<const float4*>(&xs[k][r0 + 4]);
      const float xr[8] = {xa.x, xa.y, xa.z, xa.w, xb.x, xb.y, xb.z, xb.w};
#pragma unroll
      for (int r = 0; r < 8; ++r) {
        acc[r][0] = fmaf(xr[r], wv.x, acc[r][0]);
        acc[r][1] = fmaf(xr[r], wv.y, acc[r][1]);
        acc[r][2] = fmaf(xr[r], wv.z, acc[r][2]);
        acc[r][3] = fmaf(xr[r], wv.w, acc[r][3]);
      }
    }
  }
  // write g and norms (16 threads with same rt share a row; lanes (rt&3)*16+gt)
#pragma unroll
  for (int r = 0; r < 8; ++r) {
    const int row = rb + r0 + r;
    float4 v;
    v.x = acc[r][0]; v.y = acc[r][1]; v.z = acc[r][2]; v.w = acc[r][3];
    *reinterpret_cast<float4*>(&g[(size_t)row * G_ + g0]) = v;
    float ss = v.x * v.x + v.y * v.y + v.z * v.z + v.w * v.w;
    ss += __shfl_xor(ss, 1);
    ss += __shfl_xor(ss, 2);
    ss += __shfl_xor(ss, 4);
    ss += __shfl_xor(ss, 8);
    if (gt == 0) gn[row] = sqrtf(ss);
  }
}

// ---------------- k2: sim + packed sort keys (one wave per edge) ----------
__global__ __launch_bounds__(256) void k2_sim(const float* __restrict__ g,
                                              const float* __restrict__ gn,
                                              unsigned long long* __restrict__ keys) {
  const int wid = blockIdx.x * 4 + (threadIdx.x >> 6);
  const int lane = threadIdx.x & 63;
  if (wid >= B_ * (S_ - 1)) return;
  const int b = wid / (S_ - 1);
  const int e = wid - b * (S_ - 1);
  const size_t row = (size_t)b * S_ + e;
  const float a = g[row * G_ + lane];
  const float c = g[(row + 1) * G_ + lane];
  float p = a * c;
  p += __shfl_xor(p, 1);
  p += __shfl_xor(p, 2);
  p += __shfl_xor(p, 4);
  p += __shfl_xor(p, 8);
  p += __shfl_xor(p, 16);
  p += __shfl_xor(p, 32);
  if (lane == 0) {
    const float n0 = fmaxf(gn[row], EPS_NORM);
    const float n1 = fmaxf(gn[row + 1], EPS_NORM);
    const float sim = p / (n0 * n1);
    const unsigned int u = __float_as_uint(sim);
    const unsigned int m = (u & 0x80000000u) ? ~u : (u | 0x80000000u);  // total order
    keys[(size_t)b * S_ + e] =
        ((unsigned long long)(~m) << 32) | (unsigned long long)(unsigned int)e;
  }
}

// ---------------- k3: sort + greedy + compaction (1 block per batch) ------
__global__ __launch_bounds__(512) void k3_select(const unsigned long long* __restrict__ keys,
                                                 unsigned int* __restrict__ kept) {
  __shared__ unsigned long long sk[4096];
  __shared__ unsigned char selL[4096];
  __shared__ int wsum[8];
  const int tid = threadIdx.x;
  const int b = blockIdx.x;

  for (int i = tid; i < 4096; i += 512) {
    sk[i] = (i < 4095) ? keys[(size_t)b * S_ + i] : ~0ull;
    selL[i] = 0;
  }
  __syncthreads();

  // bitonic sort ascending (key = (~mono(sim))<<32 | idx): sim desc, idx asc
  for (int k = 2; k <= 4096; k <<= 1) {
    for (int j = k >> 1; j > 0; j >>= 1) {
      for (int idx = tid; idx < 4096; idx += 512) {
        const int ixj = idx ^ j;
        if (ixj > idx) {
          const unsigned long long va = sk[idx], vb = sk[ixj];
          const bool up = ((idx & k) == 0);
          if (up ? (va > vb) : (va < vb)) { sk[idx] = vb; sk[ixj] = va; }
        }
      }
      __syncthreads();
    }
  }

  // greedy disjoint pair selection on wave 0; used-bitmask in lane registers
  if (tid < 64) {
    const int lane = tid;
    unsigned long long used = 0ull;  // lane owns nodes [lane*64, lane*64+64)
    int cnt = 0;
    for (int base = 0; base < 4095 && cnt < R_; base += 64) {
      const unsigned long long myk = sk[base + lane];
      const int myidx = (int)(unsigned int)myk;
      const int lim = (4095 - base < 64) ? (4095 - base) : 64;
      for (int i = 0; i < lim; ++i) {
        const int p = __shfl(myidx, i);
        if ((unsigned int)p >= 4095u) continue;  // pad guard (never hit)
        const int l0 = p >> 6, b0 = p & 63;
        const int l1 = (p + 1) >> 6, b1 = (p + 1) & 63;
        const unsigned int lo = (unsigned int)used;
        const unsigned int hi = (unsigned int)(used >> 32);
        const unsigned int alo = (unsigned int)__shfl((int)lo, l0);
        const unsigned int ahi = (unsigned int)__shfl((int)hi, l0);
        const unsigned long long u0 = ((unsigned long long)ahi << 32) | alo;
        unsigned long long u1 = u0;
        if (l1 != l0) {
          const unsigned int blo = (unsigned int)__shfl((int)lo, l1);
          const unsigned int bhi = (unsigned int)__shfl((int)hi, l1);
          u1 = ((unsigned long long)bhi << 32) | blo;
        }
        if (!((u0 >> b0) & 1ull) && !((u1 >> b1) & 1ull)) {
          if (lane == l0) used |= (1ull << b0);
          if (lane == l1) used |= (1ull << b1);
          if (lane == 0) selL[p] = 1;
          if (++cnt == R_) break;
        }
      }
    }
  }
  __syncthreads();

  // compaction: keep[s] = !(s>0 && sel[s-1]); stable order
  int c = 0;
  bool kp[8];
  const int s0 = tid * 8;
#pragma unroll
  for (int q = 0; q < 8; ++q) {
    const int s = s0 + q;
    const bool drop = (s > 0) && selL[s - 1];
    kp[q] = !drop;
    c += kp[q] ? 1 : 0;
  }
  const int lane = tid & 63, w = tid >> 6;
  int v = c;
#pragma unroll
  for (int off = 1; off < 64; off <<= 1) {
    const int t2 = __shfl_up(v, off);
    if (lane >= off) v += t2;
  }
  if (lane == 63) wsum[w] = v;
  __syncthreads();
  if (tid == 0) {
    int run = 0;
    for (int q = 0; q < 8; ++q) { const int t3 = wsum[q]; wsum[q] = run; run += t3; }
  }
  __syncthreads();
  int pos = (v - c) + wsum[w];
#pragma unroll
  for (int q = 0; q < 8; ++q) {
    if (kp[q]) {
      const int s = s0 + q;
      const unsigned int m = (s < 4095 && selL[s]) ? 0x80000000u : 0u;
      kept[b * SO_ + pos] = (unsigned int)s | m;
      ++pos;
    }
  }
}

// ---------------- k4: x_out + pos_out (one block per output row) ----------
__global__ __launch_bounds__(128) void k4_x(const float* __restrict__ x,
                                            const float* __restrict__ gn,
                                            const int* __restrict__ posid,
                                            const unsigned int* __restrict__ kept,
                                            float* __restrict__ outx,
                                            float* __restrict__ outpos) {
  const int blk = blockIdx.x;
  const int b = blk / SO_;
  const int j = blk - b * SO_;
  const unsigned int ent = kept[b * SO_ + j];
  const int s = (int)(ent & 0x7FFFFFFFu);
  const bool m = (ent & 0x80000000u) != 0u;
  const size_t rin = (size_t)b * S_ + s;
  const size_t rout = (size_t)b * SO_ + j;
  const int t = threadIdx.x;
  if (t == 0) outpos[rout] = (float)posid[rin];
  float4 a = *reinterpret_cast<const float4*>(&x[rin * D_ + t * 4]);
  float4 o;
  if (m) {
    const float w0 = gn[rin], w1 = gn[rin + 1];
    const float4 c2 = *reinterpret_cast<const float4*>(&x[(rin + 1) * D_ + t * 4]);
    const float den = w0 + w1 + EPS_MERGE;
    o.x = (w0 * a.x + w1 * c2.x) / den;
    o.y = (w0 * a.y + w1 * c2.y) / den;
    o.z = (w0 * a.z + w1 * c2.z) / den;
    o.w = (w0 * a.w + w1 * c2.w) / den;
  } else {
    o = a;
  }
  *reinterpret_cast<float4*>(&outx[rout * D_ + t * 4]) = o;
}

// ---------------- k5: src_out (one block per output row) ------------------
__global__ __launch_bounds__(256) void k5_src(const float* __restrict__ src,
                                              const unsigned int* __restrict__ kept,
                                              float* __restrict__ outs) {
  const int blk = blockIdx.x;
  const int b = blk / SO_;
  const int j = blk - b * SO_;
  const unsigned int ent = kept[b * SO_ + j];
  const int s = (int)(ent & 0x7FFFFFFFu);
  const bool m = (ent & 0x80000000u) != 0u;
  const size_t rin = ((size_t)b * S_ + s) * NO_;
  const size_t rout = ((size_t)b * SO_ + j) * NO_;
  const int t = threadIdx.x;
#pragma unroll
  for (int it = 0; it < 4; ++it) {
    const int f4 = t + it * 256;
    float4 a = *reinterpret_cast<const float4*>(&src[rin + (size_t)f4 * 4]);
    if (m) {
      const float4 c2 =
          *reinterpret_cast<const float4*>(&src[rin + NO_ + (size_t)f4 * 4]);
      a.x += c2.x; a.y += c2.y; a.z += c2.z; a.w += c2.w;
    }
    *reinterpret_cast<float4*>(&outs[rout + (size_t)f4 * 4]) = a;
  }
}

extern "C" void kernel_launch(void* const* d_in, const int* in_sizes, int n_in,
                              void* d_out, int out_size, void* d_ws, size_t ws_size,
                              hipStream_t stream) {
  (void)in_sizes; (void)n_in; (void)out_size; (void)ws_size;
  const float* x = (const float*)d_in[0];
  const float* src = (const float*)d_in[1];
  const int* posid = (const int*)d_in[2];
  const float* W = (const float*)d_in[3];
  // d_in[4] = r (always 1024 for this problem; shapes are compile-time)

  char* ws = (char*)d_ws;
  float* g = (float*)(ws + WS_G);
  float* gn = (float*)(ws + WS_GN);
  unsigned long long* keys = (unsigned long long*)(ws + WS_KEYS);
  unsigned int* kept = (unsigned int*)(ws + WS_KEPT);

  float* outx = (float*)d_out;
  float* outs = outx + (size_t)B_ * SO_ * D_;
  float* outpos = outs + (size_t)B_ * SO_ * NO_;

  hipLaunchKernelGGL(k1_proj, dim3(256), dim3(256), 0, stream, x, W, g, gn);
  hipLaunchKernelGGL(k2_sim, dim3((B_ * (S_ - 1)) / 4), dim3(256), 0, stream, g, gn, keys);
  hipLaunchKernelGGL(k3_select, dim3(B_), dim3(512), 0, stream, keys, kept);
  hipLaunchKernelGGL(k4_x, dim3(B_ * SO_), dim3(128), 0, stream, x, gn, posid, kept,
                     outx, outpos);
  hipLaunchKernelGGL(k5_src, dim3(B_ * SO_), dim3(256), 0, stream, src, kept, outs);
}

// Round 2
// 272.745 us; speedup vs baseline: 2.5396x; 2.5396x over previous
//
#include <hip/hip_runtime.h>
#include <hip/hip_bf16.h>
#include <stdint.h>

#define B_ 8
#define S_ 4096
#define D_ 512
#define G_ 64
#define R_ 1024
#define NO_ 4096
#define SO_ 3072   /* S_ - R_ */
#define EPS_MERGE 1e-8f
#define EPS_NORM 1e-12f

// workspace byte offsets
#define WS_G     0ull                 // g: 32768*64 f32   = 8388608 B
#define WS_GN    8388608ull           // gn: 32768 f32     = 131072 B
#define WS_KEYS  8519680ull           // prio: 8*4096 u64  = 262144 B
#define WS_KEPT  8781824ull           // kept: 8*3072 u32  = 98304 B

// ---------------- k1: g = x @ W^T  (M=32768, N=64, K=512) + row norms ----
__global__ __launch_bounds__(256) void k1_proj(const float* __restrict__ x,
                                               const float* __restrict__ W,
                                               float* __restrict__ g,
                                               float* __restrict__ gn) {
  __shared__ float xs[32][132];
  __shared__ float wc[32][68];
  const int tid = threadIdx.x;
  const int gt  = tid & 15;
  const int rt  = tid >> 4;
  const int rb  = blockIdx.x * 128;
  const int g0  = gt * 4;
  const int r0  = rt * 8;
  float acc[8][4];
#pragma unroll
  for (int r = 0; r < 8; ++r)
#pragma unroll
    for (int j = 0; j < 4; ++j) acc[r][j] = 0.f;

  for (int kc = 0; kc < 16; ++kc) {
    const int kbase = kc * 32;
    __syncthreads();
#pragma unroll
    for (int i = 0; i < 4; ++i) {
      int f4i = tid + i * 256;
      int row_l = f4i >> 3;
      int kq = f4i & 7;
      const float4 v = *reinterpret_cast<const float4*>(
          &x[(size_t)(rb + row_l) * D_ + kbase + kq * 4]);
      xs[kq * 4 + 0][row_l] = v.x;
      xs[kq * 4 + 1][row_l] = v.y;
      xs[kq * 4 + 2][row_l] = v.z;
      xs[kq * 4 + 3][row_l] = v.w;
    }
#pragma unroll
    for (int i = 0; i < 2; ++i) {
      int f4i = tid + i * 256;
      int gg = f4i >> 3;
      int kq = f4i & 7;
      const float4 v = *reinterpret_cast<const float4*>(
          &W[(size_t)gg * D_ + kbase + kq * 4]);
      wc[kq * 4 + 0][gg] = v.x;
      wc[kq * 4 + 1][gg] = v.y;
      wc[kq * 4 + 2][gg] = v.z;
      wc[kq * 4 + 3][gg] = v.w;
    }
    __syncthreads();
#pragma unroll
    for (int k = 0; k < 32; ++k) {
      const float4 wv = *reinterpret_cast<const float4*>(&wc[k][g0]);
      const float4 xa = *reinterpret_cast<const float4*>(&xs[k][r0]);
      const float4 xb = *reinterpret_cast<const float4*>(&xs[k][r0 + 4]);
      const float xr[8] = {xa.x, xa.y, xa.z, xa.w, xb.x, xb.y, xb.z, xb.w};
#pragma unroll
      for (int r = 0; r < 8; ++r) {
        acc[r][0] = fmaf(xr[r], wv.x, acc[r][0]);
        acc[r][1] = fmaf(xr[r], wv.y, acc[r][1]);
        acc[r][2] = fmaf(xr[r], wv.z, acc[r][2]);
        acc[r][3] = fmaf(xr[r], wv.w, acc[r][3]);
      }
    }
  }
#pragma unroll
  for (int r = 0; r < 8; ++r) {
    const int row = rb + r0 + r;
    float4 v;
    v.x = acc[r][0]; v.y = acc[r][1]; v.z = acc[r][2]; v.w = acc[r][3];
    *reinterpret_cast<float4*>(&g[(size_t)row * G_ + g0]) = v;
    float ss = v.x * v.x + v.y * v.y + v.z * v.z + v.w * v.w;
    ss += __shfl_xor(ss, 1);
    ss += __shfl_xor(ss, 2);
    ss += __shfl_xor(ss, 4);
    ss += __shfl_xor(ss, 8);
    if (gt == 0) gn[row] = sqrtf(ss);
  }
}

// ---------------- k2: sim -> priority key (one wave per edge) -------------
// prio[e] = mono(sim) << 32 | (4095 - e)  : strictly higher = earlier in
// greedy order (desc sim, ties -> smaller e). All keys distinct.
__global__ __launch_bounds__(256) void k2_sim(const float* __restrict__ g,
                                              const float* __restrict__ gn,
                                              unsigned long long* __restrict__ prio) {
  const int wid = blockIdx.x * 4 + (threadIdx.x >> 6);
  const int lane = threadIdx.x & 63;
  if (wid >= B_ * (S_ - 1)) return;
  const int b = wid / (S_ - 1);
  const int e = wid - b * (S_ - 1);
  const size_t row = (size_t)b * S_ + e;
  const float a = g[row * G_ + lane];
  const float c = g[(row + 1) * G_ + lane];
  float p = a * c;
  p += __shfl_xor(p, 1);
  p += __shfl_xor(p, 2);
  p += __shfl_xor(p, 4);
  p += __shfl_xor(p, 8);
  p += __shfl_xor(p, 16);
  p += __shfl_xor(p, 32);
  if (lane == 0) {
    const float n0 = fmaxf(gn[row], EPS_NORM);
    const float n1 = fmaxf(gn[row + 1], EPS_NORM);
    const float sim = p / (n0 * n1);
    const unsigned int u = __float_as_uint(sim);
    const unsigned int m = (u & 0x80000000u) ? ~u : (u | 0x80000000u);
    prio[(size_t)b * S_ + e] =
        ((unsigned long long)m << 32) | (unsigned long long)(unsigned int)(4095 - e);
  }
}

// ---------------- k3: parallel greedy matching + radix top-R + compaction -
// Lex-first maximal matching on the edge path via local-max iteration
// (exactly equals sequential greedy), then exact r-th-largest-prio
// threshold via 8-level radix select (cap equivalence: capped greedy =
// top-r by priority within uncapped matching).
__global__ __launch_bounds__(1024) void k3_match(const unsigned long long* __restrict__ prio,
                                                 unsigned int* __restrict__ kept) {
  __shared__ unsigned long long pr[4096];
  __shared__ unsigned char st[4096];   // 0=UNDEC 1=IN 2=OUT
  __shared__ int hist[256];
  __shared__ int wsum[16];
  __shared__ int sh_undec;
  __shared__ int sh_need;
  __shared__ unsigned long long sh_prefix;

  const int tid = threadIdx.x;
  const int b = blockIdx.x;

  for (int i = tid; i < 4096; i += 1024) {
    pr[i] = (i < 4095) ? prio[(size_t)b * S_ + i] : 0ull;
    st[i] = (i < 4095) ? (unsigned char)0 : (unsigned char)2;
  }
  if (tid == 0) { sh_need = R_; sh_prefix = 0ull; }

  // ---- local-max matching rounds ----
  for (;;) {
    __syncthreads();                       // A: all read previous flag
    if (tid == 0) sh_undec = 0;
    __syncthreads();                       // B
    bool any = false;
#pragma unroll
    for (int q = 0; q < 4; ++q) {
      const int e = (tid << 2) + q;
      if (e >= 4095) continue;
      if (st[e] != 0) continue;
      const unsigned char sl = e ? st[e - 1] : (unsigned char)2;
      const unsigned char sr = st[e + 1];  // e+1 <= 4095 (pad=OUT)
      if (sl == 1 || sr == 1) { st[e] = 2; continue; }
      const bool lok = (sl == 2) || (pr[e] > pr[e - 1]);
      const bool rok = (sr == 2) || (pr[e] > pr[e + 1]);
      if (lok && rok) st[e] = 1; else any = true;
    }
    if (any) sh_undec = 1;
    __syncthreads();                       // C
    if (sh_undec == 0) break;
  }

  // ---- radix select: exact R-th largest prio among IN edges ----
#pragma unroll 1
  for (int level = 0; level < 8; ++level) {
    const int shift = 56 - 8 * level;
    __syncthreads();
    if (tid < 256) hist[tid] = 0;
    __syncthreads();
    const unsigned long long pref = sh_prefix;
#pragma unroll
    for (int q = 0; q < 4; ++q) {
      const int e = (tid << 2) + q;
      if (e >= 4095) continue;
      if (st[e] != 1) continue;
      const unsigned long long p = pr[e];
      const bool match = (level == 0) || ((p >> (shift + 8)) == (pref >> (shift + 8)));
      if (match) atomicAdd(&hist[(int)((p >> shift) & 255ull)], 1);
    }
    __syncthreads();
    if (tid < 64) {
      const int lane = tid;
      const int h0 = hist[lane * 4 + 0], h1 = hist[lane * 4 + 1];
      const int h2 = hist[lane * 4 + 2], h3 = hist[lane * 4 + 3];
      const int gsum = h0 + h1 + h2 + h3;
      int s = gsum;
#pragma unroll
      for (int off = 1; off < 64; off <<= 1) {
        const int v = __shfl_down(s, off);
        if (lane + off < 64) s += v;
      }
      const int need = sh_need;            // read by all lanes before any write
      const int suffAbove = s - gsum;
      if (suffAbove < need && s >= need) { // unique lane
        const int hh[4] = {h0, h1, h2, h3};
        int cum = suffAbove;
        for (int q = 3; q >= 0; --q) {
          cum += hh[q];
          if (cum >= need) {
            sh_prefix = pref | ((unsigned long long)(lane * 4 + q) << shift);
            sh_need = need - (cum - hh[q]);
            break;
          }
        }
      }
    }
    __syncthreads();
  }
  const unsigned long long thresh = sh_prefix;   // exact R-th largest key
  __syncthreads();

  // ---- compaction: keep[s] = !(s>0 && sel[s-1]); stable order ----
  int c = 0;
  bool kp[4];
  const int s0 = tid * 4;
#pragma unroll
  for (int q = 0; q < 4; ++q) {
    const int s = s0 + q;
    const bool dropsel = (s > 0) && (st[s - 1] == 1) && (pr[s - 1] >= thresh);
    kp[q] = !dropsel;
    c += kp[q] ? 1 : 0;
  }
  const int lane = tid & 63, w = tid >> 6;
  int v = c;
#pragma unroll
  for (int off = 1; off < 64; off <<= 1) {
    const int t2 = __shfl_up(v, off);
    if (lane >= off) v += t2;
  }
  if (lane == 63) wsum[w] = v;
  __syncthreads();
  if (tid == 0) {
    int run = 0;
    for (int q = 0; q < 16; ++q) { const int t3 = wsum[q]; wsum[q] = run; run += t3; }
  }
  __syncthreads();
  int pos = (v - c) + wsum[w];
#pragma unroll
  for (int q = 0; q < 4; ++q) {
    if (kp[q]) {
      const int s = s0 + q;
      const unsigned int m =
          (s < 4095 && st[s] == 1 && pr[s] >= thresh) ? 0x80000000u : 0u;
      kept[b * SO_ + pos] = (unsigned int)s | m;
      ++pos;
    }
  }
}

// ---------------- k4: x_out + pos_out (one block per output row) ----------
__global__ __launch_bounds__(128) void k4_x(const float* __restrict__ x,
                                            const float* __restrict__ gn,
                                            const int* __restrict__ posid,
                                            const unsigned int* __restrict__ kept,
                                            float* __restrict__ outx,
                                            float* __restrict__ outpos) {
  const int blk = blockIdx.x;
  const int b = blk / SO_;
  const int j = blk - b * SO_;
  const unsigned int ent = kept[b * SO_ + j];
  const int s = (int)(ent & 0x7FFFFFFFu);
  const bool m = (ent & 0x80000000u) != 0u;
  const size_t rin = (size_t)b * S_ + s;
  const size_t rout = (size_t)b * SO_ + j;
  const int t = threadIdx.x;
  if (t == 0) outpos[rout] = (float)posid[rin];
  float4 a = *reinterpret_cast<const float4*>(&x[rin * D_ + t * 4]);
  float4 o;
  if (m) {
    const float w0 = gn[rin], w1 = gn[rin + 1];
    const float4 c2 = *reinterpret_cast<const float4*>(&x[(rin + 1) * D_ + t * 4]);
    const float den = w0 + w1 + EPS_MERGE;
    o.x = (w0 * a.x + w1 * c2.x) / den;
    o.y = (w0 * a.y + w1 * c2.y) / den;
    o.z = (w0 * a.z + w1 * c2.z) / den;
    o.w = (w0 * a.w + w1 * c2.w) / den;
  } else {
    o = a;
  }
  *reinterpret_cast<float4*>(&outx[rout * D_ + t * 4]) = o;
}

// ---------------- k5: src_out (one block per output row) ------------------
__global__ __launch_bounds__(256) void k5_src(const float* __restrict__ src,
                                              const unsigned int* __restrict__ kept,
                                              float* __restrict__ outs) {
  const int blk = blockIdx.x;
  const int b = blk / SO_;
  const int j = blk - b * SO_;
  const unsigned int ent = kept[b * SO_ + j];
  const int s = (int)(ent & 0x7FFFFFFFu);
  const bool m = (ent & 0x80000000u) != 0u;
  const size_t rin = ((size_t)b * S_ + s) * NO_;
  const size_t rout = ((size_t)b * SO_ + j) * NO_;
  const int t = threadIdx.x;
#pragma unroll
  for (int it = 0; it < 4; ++it) {
    const int f4 = t + it * 256;
    float4 a = *reinterpret_cast<const float4*>(&src[rin + (size_t)f4 * 4]);
    if (m) {
      const float4 c2 =
          *reinterpret_cast<const float4*>(&src[rin + NO_ + (size_t)f4 * 4]);
      a.x += c2.x; a.y += c2.y; a.z += c2.z; a.w += c2.w;
    }
    *reinterpret_cast<float4*>(&outs[rout + (size_t)f4 * 4]) = a;
  }
}

extern "C" void kernel_launch(void* const* d_in, const int* in_sizes, int n_in,
                              void* d_out, int out_size, void* d_ws, size_t ws_size,
                              hipStream_t stream) {
  (void)in_sizes; (void)n_in; (void)out_size; (void)ws_size;
  const float* x = (const float*)d_in[0];
  const float* src = (const float*)d_in[1];
  const int* posid = (const int*)d_in[2];
  const float* W = (const float*)d_in[3];

  char* ws = (char*)d_ws;
  float* g = (float*)(ws + WS_G);
  float* gn = (float*)(ws + WS_GN);
  unsigned long long* prio = (unsigned long long*)(ws + WS_KEYS);
  unsigned int* kept = (unsigned int*)(ws + WS_KEPT);

  float* outx = (float*)d_out;
  float* outs = outx + (size_t)B_ * SO_ * D_;
  float* outpos = outs + (size_t)B_ * SO_ * NO_;

  hipLaunchKernelGGL(k1_proj, dim3(256), dim3(256), 0, stream, x, W, g, gn);
  hipLaunchKernelGGL(k2_sim, dim3((B_ * (S_ - 1) + 3) / 4), dim3(256), 0, stream, g, gn, prio);
  hipLaunchKernelGGL(k3_match, dim3(B_), dim3(1024), 0, stream, prio, kept);
  hipLaunchKernelGGL(k4_x, dim3(B_ * SO_), dim3(128), 0, stream, x, gn, posid, kept,
                     outx, outpos);
  hipLaunchKernelGGL(k5_src, dim3(B_ * SO_), dim3(256), 0, stream, src, kept, outs);
}